// Round 10
// baseline (88.353 us; speedup 1.0000x reference)
//
#include <hip/hip_runtime.h>

typedef float f32x4 __attribute__((ext_vector_type(4)));
typedef __bf16 bf16x8 __attribute__((ext_vector_type(8)));
typedef unsigned short u16x8 __attribute__((ext_vector_type(8)));

__device__ __forceinline__ unsigned short f2bf(float f) {
  union { float f; unsigned u; } v; v.f = f;
  unsigned r = v.u + 0x7FFFu + ((v.u >> 16) & 1u);
  return (unsigned short)(r >> 16);
}

__device__ __forceinline__ float min3f(float a, float b, float c) {
  return fminf(fminf(a, b), c);
}
__device__ __forceinline__ float max3f(float a, float b, float c) {
  return fmaxf(fmaxf(a, b), c);
}
__device__ __forceinline__ float med3f(float a, float b, float c) {
  return __builtin_amdgcn_fmed3f(a, b, c);
}

// async global->LDS, 16B per lane, LDS dest = wave-uniform base + lane*16
__device__ __forceinline__ void gload_lds16(const void* g, void* l) {
  __builtin_amdgcn_global_load_lds(
      (const __attribute__((address_space(1))) void*)g,
      (__attribute__((address_space(3))) void*)l, 16, 0, 0);
}

// conv_w fp32 [256][256] -> bf16 in MFMA-fragment-linear order:
// wbf[((ks*16 + ob)*64 + lane)*8 + j] = bf16(W[ob*16 + (lane&15)][ks*32 + (lane>>4)*8 + j])
__global__ void wconv_k(const float* __restrict__ w, unsigned short* __restrict__ wbf) {
  int idx  = blockIdx.x * 256 + threadIdx.x;   // 0..8191
  int lane = idx & 63;
  int ob   = (idx >> 6) & 15;
  int ks   = idx >> 10;                        // 0..7
  int o = (ob << 4) + (lane & 15);
  int c = (ks << 5) + ((lane >> 4) << 3);
  const float* src = w + (o << 8) + c;
  f32x4 v0 = *(const f32x4*)src;
  f32x4 v1 = *(const f32x4*)(src + 4);
  u16x8 ov;
  ov[0] = f2bf(v0[0]); ov[1] = f2bf(v0[1]); ov[2] = f2bf(v0[2]); ov[3] = f2bf(v0[3]);
  ov[4] = f2bf(v1[0]); ov[5] = f2bf(v1[1]); ov[6] = f2bf(v1[2]); ov[7] = f2bf(v1[3]);
  *(u16x8*)(wbf + (idx << 3)) = ov;
}

// One block = one (batch, row). Xs is WAVE-PRIVATE and double-buffered;
// stage(ks+2) issued at step ks AFTER a per-wave lgkmcnt(0) WAR fence
// (median ds_reads of the same buffer must COMPLETE before re-staging --
// this was R9's race). VMEM queue order pinned [.., wf(ks), stage(ks+2)]
// so the compiler's pre-MFMA wf-wait is vmcnt(6): stage(ks+2) stays in
// flight across the whole step. No vmcnt-draining barrier in the loop.
__launch_bounds__(256, 3)
__global__ void fused_k(const float* __restrict__ x,
                        const unsigned short* __restrict__ wbf,
                        const float* __restrict__ bias,
                        float* __restrict__ out) {
  __shared__ float Xs[2][96][64];            // 48 KB, px-block pre-swizzled
  __shared__ unsigned short Bt[64][40];      //  5 KB med tile [px][c-swizzled]

  const int t   = threadIdx.x;
  const int blk = blockIdx.x;
  const int swz = ((blk & 7) << 8) | (blk >> 3);   // XCD-bijective (2048 = 8*256)
  const int b   = swz >> 6;
  const int r   = swz & 63;
  const int lane = t & 63;
  const int w    = t >> 6;       // wave 0..3
  const int g    = lane >> 4;    // lane group 0..3
  const int l15  = lane & 15;

  // median task: channel ci = t>>3 (0..31), pixel strip s = t&7 (8 px)
  const int ci  = t >> 3;
  const int s   = t & 7;
  const int px0 = s << 3;
  const int cw  = ci ^ ((s & 3) << 3);   // Bt bank-deconflict swizzle
  const bool rT = (r >= 1), rB = (r <= 62);
  const bool hasL = (s > 0), hasR = (s < 7);

  const float* xb = x + ((size_t)b << 20);   // b * 256*64*64

  // bias for this thread's 4 o-blocks (o = w*64 + n*16 + l15)
  float bn[4];
  #pragma unroll
  for (int n = 0; n < 4; ++n) bn[n] = bias[(w << 6) + (n << 4) + l15];

  // --- staging source byte-offsets (wave w stages rows w*24 .. w*24+23) ---
  unsigned soff[6];
  #pragma unroll
  for (int p = 0; p < 6; ++p) {
    int row = w * 24 + (p << 2) + (lane >> 4);
    int cip = (row * 171) >> 9;            // row / 3 (exact for row < 96)
    int drp = row - cip * 3;
    int gr  = r + drp - 1;
    gr = gr < 0 ? 0 : (gr > 63 ? 63 : gr); // clamp; zeroed in VALU at median time
    int bG  = (lane & 15) ^ (cip & 7);     // pre-swizzled global px-block
    soff[p] = ((unsigned)cip << 14) + ((unsigned)gr << 8) + ((unsigned)bG << 4);
  }

  // loop-invariant swizzled LDS read block indices
  const int ri0 = ci * 3;
  const int sig = ci & 7;
  const int bAi = ((s << 1)) ^ sig;
  const int bBi = ((s << 1) | 1) ^ sig;

  auto stage = [&](int step, int buf) {
    const unsigned kso = (unsigned)step << 19;   // step * 32ch * 4096px * 4B
    #pragma unroll
    for (int p = 0; p < 6; ++p)
      gload_lds16((const char*)xb + (soff[p] + kso), &Xs[buf][w * 24 + (p << 2)][0]);
  };

  f32x4 acc[4][4];
  #pragma unroll
  for (int m = 0; m < 4; ++m)
    #pragma unroll
    for (int n = 0; n < 4; ++n)
      acc[m][n] = (f32x4){0.f, 0.f, 0.f, 0.f};

  // --- prologue: two tiles in flight ---
  stage(0, 0);
  stage(1, 1);

  #pragma unroll
  for (int ks = 0; ks < 8; ++ks) {
    // (a) stage(ks) landed: queue order guarantees any wf-covering wait at
    //     step ks-1's MFMA already drained it; this is a steady-state no-op.
    asm volatile("s_waitcnt vmcnt(6)" ::: "memory");
    __builtin_amdgcn_sched_barrier(0);

    // (b) median source reads from wave-private Xs[ks&1]
    f32x4 va[3], vb[3];
    #pragma unroll
    for (int dr = 0; dr < 3; ++dr) {
      const float* rp = &Xs[ks & 1][ri0 + dr][0];
      va[dr] = *(const f32x4*)(rp + (bAi << 2));
      vb[dr] = *(const f32x4*)(rp + (bBi << 2));
    }
    // (b2) WAR fence: reads must COMPLETE before stage(ks+2) rewrites this
    //      buffer (per-wave, no barrier). This was R9's race.
    asm volatile("s_waitcnt lgkmcnt(0)" ::: "memory");
    __builtin_amdgcn_sched_barrier(0);

    // (c1) W fragments for THIS step (older in VMEM queue than stage)
    bf16x8 wfc[4];
    #pragma unroll
    for (int n = 0; n < 4; ++n) {
      const int fidx = (((ks << 4) + (w << 2) + n) << 6) + lane;
      wfc[n] = __builtin_bit_cast(bf16x8, *(const u16x8*)(wbf + ((size_t)fidx << 3)));
    }
    __builtin_amdgcn_sched_barrier(0);
    // (c2) stage(ks+2) into the buffer just consumed
    if (ks < 6) stage(ks + 2, ks & 1);
    __builtin_amdgcn_sched_barrier(0);

    // (d) median compute (halo via lane shuffles) + Bt store
    {
      float R[3][10];
      #pragma unroll
      for (int dr = 0; dr < 3; ++dr) {
        float le = __shfl_up(vb[dr][3], 1);    // left halo from lane-1
        float re = __shfl_down(va[dr][0], 1);  // right halo from lane+1
        R[dr][0] = hasL ? le : 0.f;
        R[dr][9] = hasR ? re : 0.f;
        #pragma unroll
        for (int j = 0; j < 4; ++j) { R[dr][1 + j] = va[dr][j]; R[dr][5 + j] = vb[dr][j]; }
      }
      if (!rT) {                     // uniform per block (r==0 only)
        #pragma unroll
        for (int j = 0; j < 10; ++j) R[0][j] = 0.f;
      }
      if (!rB) {                     // uniform per block (r==63 only)
        #pragma unroll
        for (int j = 0; j < 10; ++j) R[2][j] = 0.f;
      }
      float mn[10], md[10], mx[10];
      #pragma unroll
      for (int j = 0; j < 10; ++j) {
        mn[j] = min3f(R[0][j], R[1][j], R[2][j]);
        md[j] = med3f(R[0][j], R[1][j], R[2][j]);
        mx[j] = max3f(R[0][j], R[1][j], R[2][j]);
      }
      #pragma unroll
      for (int i = 0; i < 8; ++i) {
        float t0 = max3f(mn[i], mn[i+1], mn[i+2]);
        float t1 = med3f(md[i], md[i+1], md[i+2]);
        float t2 = min3f(mx[i], mx[i+1], mx[i+2]);
        Bt[px0 + i][cw] = f2bf(med3f(t0, t1, t2));
      }
    }

    // (e) publish Bt: LDS drain + raw barrier (NO vmcnt drain)
    asm volatile("s_waitcnt lgkmcnt(0)\n\ts_barrier" ::: "memory");
    __builtin_amdgcn_sched_barrier(0);

    // (f) P fragments (med tile, A-operand)
    bf16x8 pa[4];
    #pragma unroll
    for (int m = 0; m < 4; ++m) {
      const int px = (m << 4) + l15;
      const int gc = (g ^ ((px >> 3) & 3)) << 3;
      pa[m] = __builtin_bit_cast(bf16x8, *(const u16x8*)&Bt[px][gc]);
    }

    // (g) MFMA (compiler waits lgkmcnt for pa + vmcnt(6) for wfc)
    __builtin_amdgcn_s_setprio(1);
    #pragma unroll
    for (int m = 0; m < 4; ++m)
      #pragma unroll
      for (int n = 0; n < 4; ++n)
        acc[m][n] = __builtin_amdgcn_mfma_f32_16x16x32_bf16(pa[m], wfc[n], acc[m][n], 0, 0, 0);
    __builtin_amdgcn_s_setprio(0);

    // (h) all waves' pa reads completed (pre-MFMA lgkmcnt) -> Bt reusable
    asm volatile("s_barrier" ::: "memory");
    __builtin_amdgcn_sched_barrier(0);
  }

  // --- epilogue: out = x + acc + bias; q maps to px -> f32x4 I/O ---
  // C layout: row = g*4+q -> px = m*16+g*4+q ; col = l15 -> o = w*64+n*16+l15
  #pragma unroll
  for (int m = 0; m < 4; ++m) {
    #pragma unroll
    for (int n = 0; n < 4; ++n) {
      const int o = (w << 6) + (n << 4) + l15;
      const size_t idx = ((((size_t)b << 8) + (size_t)o) << 12) + ((size_t)r << 6)
                       + (size_t)((m << 4) + (g << 2));
      f32x4 xv = *(const f32x4*)(x + idx);
      f32x4 res;
      #pragma unroll
      for (int q = 0; q < 4; ++q) res[q] = xv[q] + acc[m][n][q] + bn[n];
      *(f32x4*)(out + idx) = res;
    }
  }
}

extern "C" void kernel_launch(void* const* d_in, const int* in_sizes, int n_in,
                              void* d_out, int out_size, void* d_ws, size_t ws_size,
                              hipStream_t stream) {
  const float* x  = (const float*)d_in[0];
  const float* cw = (const float*)d_in[1];
  const float* cb = (const float*)d_in[2];
  float* out = (float*)d_out;
  unsigned short* wbf = (unsigned short*)d_ws;   // 128 KB fragment-linear W

  hipLaunchKernelGGL(wconv_k, dim3(32), dim3(256), 0, stream, cw, wbf);
  hipLaunchKernelGGL(fused_k, dim3(2048), dim3(256), 0, stream, x, wbf, cb, out);
}

// Round 11
// 65.588 us; speedup vs baseline: 1.3471x; 1.3471x over previous
//
#include <hip/hip_runtime.h>

typedef float f32x4 __attribute__((ext_vector_type(4)));
typedef __bf16 bf16x8 __attribute__((ext_vector_type(8)));
typedef unsigned short u16x8 __attribute__((ext_vector_type(8)));

__device__ __forceinline__ unsigned short f2bf(float f) {
  union { float f; unsigned u; } v; v.f = f;
  unsigned r = v.u + 0x7FFFu + ((v.u >> 16) & 1u);
  return (unsigned short)(r >> 16);
}

__device__ __forceinline__ float min3f(float a, float b, float c) {
  return fminf(fminf(a, b), c);
}
__device__ __forceinline__ float max3f(float a, float b, float c) {
  return fmaxf(fmaxf(a, b), c);
}
__device__ __forceinline__ float med3f(float a, float b, float c) {
  return __builtin_amdgcn_fmed3f(a, b, c);
}

// async global->LDS, 16B per lane, LDS dest = wave-uniform base + lane*16
__device__ __forceinline__ void gload_lds16(const void* g, void* l) {
  __builtin_amdgcn_global_load_lds(
      (const __attribute__((address_space(1))) void*)g,
      (__attribute__((address_space(3))) void*)l, 16, 0, 0);
}

// conv_w fp32 [256][256] -> bf16 in MFMA-fragment-linear order:
// wbf[((ks*16 + ob)*64 + lane)*8 + j] = bf16(W[ob*16 + (lane&15)][ks*32 + (lane>>4)*8 + j])
__global__ void wconv_k(const float* __restrict__ w, unsigned short* __restrict__ wbf) {
  int idx  = blockIdx.x * 256 + threadIdx.x;   // 0..8191
  int lane = idx & 63;
  int ob   = (idx >> 6) & 15;
  int ks   = idx >> 10;                        // 0..7
  int o = (ob << 4) + (lane & 15);
  int c = (ks << 5) + ((lane >> 4) << 3);
  const float* src = w + (o << 8) + c;
  f32x4 v0 = *(const f32x4*)src;
  f32x4 v1 = *(const f32x4*)(src + 4);
  u16x8 ov;
  ov[0] = f2bf(v0[0]); ov[1] = f2bf(v0[1]); ov[2] = f2bf(v0[2]); ov[3] = f2bf(v0[3]);
  ov[4] = f2bf(v1[0]); ov[5] = f2bf(v1[1]); ov[6] = f2bf(v1[2]); ov[7] = f2bf(v1[3]);
  *(u16x8*)(wbf + (idx << 3)) = ov;
}

// One block = one (batch, row-PAIR): 128 output px x 256 oc. Stage 32ch x
// 4 rows per step (halo cost (R+2)/R = 2x), wf amortized over 128 px, and
// the residual x is folded from the staged Xs tile (write-only epilogue).
// Simple R6-style 2-barrier step (proven correct & fastest structure).
__launch_bounds__(256, 2)
__global__ void fused_k(const float* __restrict__ x,
                        const unsigned short* __restrict__ wbf,
                        const float* __restrict__ bias,
                        float* __restrict__ out) {
  __shared__ float Xs[128][64];            // 32 KB: row = ci*4 + dr, px-block swizzled
  __shared__ unsigned short Bt[128][40];   // 10 KB: [px'][c-swizzled]

  const int t   = threadIdx.x;
  const int blk = blockIdx.x;
  const int swz = ((blk & 7) << 7) | (blk >> 3);   // XCD-bijective (1024 = 8*128)
  const int b   = swz >> 5;
  const int r0  = (swz & 31) << 1;         // even row, rows r0 and r0+1
  const int lane = t & 63;
  const int w    = t >> 6;       // wave 0..3
  const int g    = lane >> 4;    // lane group 0..3
  const int l15  = lane & 15;

  // median task: channel ci = t>>3 (0..31), strip s = t&7 (8 px, both rows)
  const int ci  = t >> 3;
  const int s   = t & 7;
  const int px0 = s << 3;
  const int cw  = ci ^ ((s & 3) << 3);     // Bt bank-deconflict swizzle
  const bool hasL = (s > 0), hasR = (s < 7);
  const bool zTop = (r0 == 0), zBot = (r0 == 62);

  const float* xb = x + ((size_t)b << 20);   // b * 256*64*64

  float bn[4];
  #pragma unroll
  for (int n = 0; n < 4; ++n) bn[n] = bias[(w << 6) + (n << 4) + l15];

  // staging: issue p stages channel cp=8w+p, rows dr=lane>>4 (4 rows = 1 KB)
  unsigned soff[8];
  #pragma unroll
  for (int p = 0; p < 8; ++p) {
    int cp = (w << 3) + p;
    int gr = r0 + (lane >> 4) - 1;
    gr = gr < 0 ? 0 : (gr > 63 ? 63 : gr);   // clamp; zeroed in VALU at median
    int bG = (lane & 15) ^ p;                // pre-swizzle px-block by cp&7==p
    soff[p] = ((unsigned)cp << 14) + ((unsigned)gr << 8) + ((unsigned)bG << 4);
  }

  auto stage = [&](int step) {
    const unsigned kso = (unsigned)step << 19;   // step * 32ch * 16KB
    #pragma unroll
    for (int p = 0; p < 8; ++p)
      gload_lds16((const char*)xb + (soff[p] + kso), &Xs[(w << 5) + (p << 2)][0]);
  };

  f32x4 acc[8][4];
  #pragma unroll
  for (int m = 0; m < 8; ++m)
    #pragma unroll
    for (int n = 0; n < 4; ++n)
      acc[m][n] = (f32x4){0.f, 0.f, 0.f, 0.f};

  stage(0);
  __syncthreads();

  const int ri0 = ci << 2;
  const int sig = ci & 7;
  const int bA  = ((s << 1)) ^ sig;
  const int bB  = ((s << 1) | 1) ^ sig;

  #pragma unroll
  for (int ks = 0; ks < 8; ++ks) {
    // --- W fragments (L2-hot, coalesced) ---
    bf16x8 wfc[4];
    #pragma unroll
    for (int n = 0; n < 4; ++n) {
      const int fidx = (((ks << 4) + (w << 2) + n) << 6) + lane;
      wfc[n] = __builtin_bit_cast(bf16x8, *(const u16x8*)(wbf + ((size_t)fidx << 3)));
    }

    // --- median source reads: 4 rows x 2 vecs ---
    f32x4 va[4], vb[4];
    #pragma unroll
    for (int dr = 0; dr < 4; ++dr) {
      const float* rp = &Xs[ri0 + dr][0];
      va[dr] = *(const f32x4*)(rp + (bA << 2));
      vb[dr] = *(const f32x4*)(rp + (bB << 2));
    }
    float le[4], re[4];
    #pragma unroll
    for (int dr = 0; dr < 4; ++dr) {
      le[dr] = __shfl_up(vb[dr][3], 1);
      re[dr] = __shfl_down(va[dr][0], 1);
    }

    // --- residual fold: at step ks = 2w+h, staged channels ARE wave w's
    //     out-channels for n in {2h, 2h+1}; rows r0,r0+1 = dr 1,2 ---
    if ((ks >> 1) == w) {
      const int h = ks & 1;
      #pragma unroll
      for (int nn = 0; nn < 2; ++nn) {
        const int n  = (h << 1) + nn;
        const int cx = (nn << 4) + l15;
        const int sx = cx & 7;
        const int rb = cx << 2;
        #pragma unroll
        for (int m = 0; m < 8; ++m) {
          const int bL = ((((m & 3) << 2) + g) ^ sx) << 2;
          const f32x4 xv = *(const f32x4*)&Xs[rb + 1 + (m >> 2)][bL];
          acc[m][n] += xv;
        }
      }
    }

    // --- strip A (output row r0): staged rows 0,1,2 ---
    {
      float R0[10], R1[10], R2[10];
      R0[0] = hasL ? le[0] : 0.f; R1[0] = hasL ? le[1] : 0.f; R2[0] = hasL ? le[2] : 0.f;
      R0[9] = hasR ? re[0] : 0.f; R1[9] = hasR ? re[1] : 0.f; R2[9] = hasR ? re[2] : 0.f;
      #pragma unroll
      for (int j = 0; j < 4; ++j) {
        R0[1 + j] = va[0][j]; R0[5 + j] = vb[0][j];
        R1[1 + j] = va[1][j]; R1[5 + j] = vb[1][j];
        R2[1 + j] = va[2][j]; R2[5 + j] = vb[2][j];
      }
      if (zTop) {
        #pragma unroll
        for (int j = 0; j < 10; ++j) R0[j] = 0.f;
      }
      float mn[10], md[10], mx[10];
      #pragma unroll
      for (int j = 0; j < 10; ++j) {
        mn[j] = min3f(R0[j], R1[j], R2[j]);
        md[j] = med3f(R0[j], R1[j], R2[j]);
        mx[j] = max3f(R0[j], R1[j], R2[j]);
      }
      #pragma unroll
      for (int i = 0; i < 8; ++i) {
        float t0 = max3f(mn[i], mn[i+1], mn[i+2]);
        float t1 = med3f(md[i], md[i+1], md[i+2]);
        float t2 = min3f(mx[i], mx[i+1], mx[i+2]);
        Bt[px0 + i][cw] = f2bf(med3f(t0, t1, t2));
      }
    }
    // --- strip B (output row r0+1): staged rows 1,2,3 ---
    {
      float R0[10], R1[10], R2[10];
      R0[0] = hasL ? le[1] : 0.f; R1[0] = hasL ? le[2] : 0.f; R2[0] = hasL ? le[3] : 0.f;
      R0[9] = hasR ? re[1] : 0.f; R1[9] = hasR ? re[2] : 0.f; R2[9] = hasR ? re[3] : 0.f;
      #pragma unroll
      for (int j = 0; j < 4; ++j) {
        R0[1 + j] = va[1][j]; R0[5 + j] = vb[1][j];
        R1[1 + j] = va[2][j]; R1[5 + j] = vb[2][j];
        R2[1 + j] = va[3][j]; R2[5 + j] = vb[3][j];
      }
      if (zBot) {
        #pragma unroll
        for (int j = 0; j < 10; ++j) R2[j] = 0.f;
      }
      float mn[10], md[10], mx[10];
      #pragma unroll
      for (int j = 0; j < 10; ++j) {
        mn[j] = min3f(R0[j], R1[j], R2[j]);
        md[j] = med3f(R0[j], R1[j], R2[j]);
        mx[j] = max3f(R0[j], R1[j], R2[j]);
      }
      #pragma unroll
      for (int i = 0; i < 8; ++i) {
        float t0 = max3f(mn[i], mn[i+1], mn[i+2]);
        float t1 = med3f(md[i], md[i+1], md[i+2]);
        float t2 = min3f(mx[i], mx[i+1], mx[i+2]);
        Bt[64 + px0 + i][cw] = f2bf(med3f(t0, t1, t2));
      }
    }

    __syncthreads();   // publish Bt; Xs reads complete (lgkm drained)

    if (ks < 7) stage(ks + 1);   // overwrite Xs (safe), drains at next barrier

    // --- P fragments + MFMA: px' = m*16+l15 (m 0..7), oc = w*64+n*16+l15 ---
    bf16x8 pa[8];
    #pragma unroll
    for (int m = 0; m < 8; ++m) {
      const int px = (m << 4) + l15;
      const int gc = (g ^ ((px >> 3) & 3)) << 3;
      pa[m] = __builtin_bit_cast(bf16x8, *(const u16x8*)&Bt[px][gc]);
    }
    #pragma unroll
    for (int m = 0; m < 8; ++m)
      #pragma unroll
      for (int n = 0; n < 4; ++n)
        acc[m][n] = __builtin_amdgcn_mfma_f32_16x16x32_bf16(pa[m], wfc[n], acc[m][n], 0, 0, 0);

    if (ks < 7) __syncthreads();   // stage landed + Bt consumed
  }

  // --- epilogue (write-only): px' = m*16+g*4+q, row = r0 + (m>>2) ---
  #pragma unroll
  for (int m = 0; m < 8; ++m) {
    #pragma unroll
    for (int n = 0; n < 4; ++n) {
      const int o = (w << 6) + (n << 4) + l15;
      const size_t idx = ((((size_t)b << 8) + (size_t)o) << 12)
                       + ((size_t)(r0 + (m >> 2)) << 6)
                       + (size_t)(((m & 3) << 4) + (g << 2));
      f32x4 res;
      #pragma unroll
      for (int q = 0; q < 4; ++q) res[q] = acc[m][n][q] + bn[n];
      *(f32x4*)(out + idx) = res;
    }
  }
}

extern "C" void kernel_launch(void* const* d_in, const int* in_sizes, int n_in,
                              void* d_out, int out_size, void* d_ws, size_t ws_size,
                              hipStream_t stream) {
  const float* x  = (const float*)d_in[0];
  const float* cw = (const float*)d_in[1];
  const float* cb = (const float*)d_in[2];
  float* out = (float*)d_out;
  unsigned short* wbf = (unsigned short*)d_ws;   // 128 KB fragment-linear W

  hipLaunchKernelGGL(wconv_k, dim3(32), dim3(256), 0, stream, cw, wbf);
  hipLaunchKernelGGL(fused_k, dim3(1024), dim3(256), 0, stream, x, wbf, cb, out);
}